// Round 14
// baseline (4970.671 us; speedup 1.0000x reference)
//
#include <hip/hip_runtime.h>
#include <stdint.h>

#define TSTEPS 512
#define BATCH  64
#define HDIM   512
#define GATE   2048
#define ACTMAT (BATCH * HDIM)   // 32768 activations per timestep matrix
#define SENT   0xFFFFFFFFu      // f16 NaN-pair sentinel; |h|<1 so never produced
#define NWGTOT 256              // 1 WG/CU exactly (128KB LDS forces 1/CU)

typedef __attribute__((ext_vector_type(8))) _Float16 f16x8;
typedef __attribute__((ext_vector_type(4))) float f32x4;
typedef __attribute__((ext_vector_type(4))) uint32_t u32x4;
typedef __attribute__((ext_vector_type(2))) uint32_t u32x2;

__device__ __forceinline__ unsigned short f2h(float f) {
  union { _Float16 h; unsigned short u; } v;
  v.h = (_Float16)f;                                 // RNE f32->f16
  return v.u;
}
__device__ __forceinline__ float fsigmoid(float x) {
  return 1.0f / (1.0f + __expf(-x));
}

// ---------------- pre-kernels ----------------

// Sentinel-init h buffers (t=0 slice = 0); zero ctrs via AGENT-scope atomics
// (plain stores can sit dirty in an init-XCD L2 while workers' MALL-side RMWs
// would read stale values on graph replay).
__global__ void init_h(unsigned short* h0, unsigned short* h1, int* ctrs) {
  size_t u = (size_t)blockIdx.x * blockDim.x + threadIdx.x;   // 16B unit index
  if (u < 16)
    __hip_atomic_store(&ctrs[u], 0, __ATOMIC_RELAXED, __HIP_MEMORY_SCOPE_AGENT);
  u32x4 v;
  if (u < (ACTMAT * 2 / 16)) v = (u32x4){0u, 0u, 0u, 0u};
  else                       v = (u32x4){SENT, SENT, SENT, SENT};
  ((u32x4*)h0)[u] = v;
  ((u32x4*)h1)[u] = v;
}

__global__ void convert_x(const float* __restrict__ x, unsigned short* __restrict__ xh) {
  size_t i = (size_t)(blockIdx.x * blockDim.x + threadIdx.x) * 4;
  float4 v = *(const float4*)(x + i);
  ushort4 o = make_ushort4(f2h(v.x), f2h(v.y), f2h(v.z), f2h(v.w));
  *(ushort4*)(xh + i) = o;
}

// Fuse [Wi | Wh] into [GATE][1024], single f16 panel.
__global__ void split_w(const float* __restrict__ Wi, const float* __restrict__ Wh,
                        unsigned short* __restrict__ Wf) {
  int i = blockIdx.x * blockDim.x + threadIdx.x;     // over GATE*1024
  int G = i >> 10, k = i & 1023;
  float w = (k < 512) ? Wi[((size_t)G << 9) + k] : Wh[((size_t)G << 9) + (k - 512)];
  Wf[i] = f2h(w);
}

// ---------------- persistent recurrence kernel ----------------
// Round-11 GEMM core (32 rows x 16 cols per WG, 2 waves, 128KB f16 LDS weights,
// zero-shuffle epilogue) + XCD-LOCAL self-recurrence.
// LDS DISCIPLINE: static LDS must be <= 131072 B total (R12/R13 aborted at launch
// with 131088). Role words live in wlds[0][0..3] during the role phase, then weight
// staging overwrites them (double barrier in between).
// Groups (layer,p) = XCD 0..3, defined by HW_REG_XCC_ID claim -> intra-group
// locality by construction. FAST iff XCDs 0-3 each host >=32 WGs (leader elects
// after bounded rendezvous, publishes via MALL word); else FALLBACK = exact R11.
// Producers DUAL-STORE the same address: plain dwordx2 (write-through L1 -> own
// XCD L2: fast path) + sc0sc1 dwordx2 (MALL: always-present fallback copy).
// Consumers (self-recurrence, FAST): plain speculative issue; bounded tiered retry:
// <=24x sc1-only loads (device scope, bypasses L1 -> no stale-L1 trap), then proven
// sc0sc1. Every path returns data or sentinel->retry; MALL copy always exists ->
// no livelock; worst case == R11 behavior. Cross-layer h0 stays sc0sc1-only.

__global__ __launch_bounds__(128, 1)
void sublstm_persistent(const unsigned short* __restrict__ xh,
                        unsigned short* h0, unsigned short* h1,
                        const unsigned short* __restrict__ Wf0,
                        const unsigned short* __restrict__ Wf1,
                        const float* __restrict__ bi0, const float* __restrict__ bi1,
                        float* __restrict__ out, int* ctrs)
{
  __shared__ unsigned short wlds[64][1024];          // 131072 B EXACTLY; nothing else

  const int tid  = threadIdx.x;
  const int lane = tid & 63;
  const int wr   = tid >> 6;                         // wave 0/1 = row-half

  volatile int* roleShare = (volatile int*)&wlds[0][0];

  // ---- role phase: XCD discovery, bounded rendezvous, mode election ----
  if (tid == 0) {
    int xcc;
    asm volatile("s_getreg_b32 %0, hwreg(HW_REG_XCC_ID)" : "=s"(xcc));
    xcc &= 7;
    int slot = atomicAdd(&ctrs[xcc], 1);             // per-XCD slot (MALL RMW, proven)
    int g    = atomicAdd(&ctrs[8], 1);               // global ticket
    atomicAdd(&ctrs[9], 1);                          // arrival count
    if (g == 0) {                                    // leader: bounded wait, publish mode
      for (int it = 0; it < (1 << 20); ++it) {
        if (__hip_atomic_load(&ctrs[9], __ATOMIC_RELAXED, __HIP_MEMORY_SCOPE_AGENT)
            >= NWGTOT) break;
        __builtin_amdgcn_s_sleep(8);
      }
      int ok = 1;
      for (int xx = 0; xx < 4; ++xx)
        if (__hip_atomic_load(&ctrs[xx], __ATOMIC_RELAXED, __HIP_MEMORY_SCOPE_AGENT) < 32)
          ok = 0;
      __hip_atomic_store(&ctrs[10], ok ? 1 : 2, __ATOMIC_RELAXED,
                         __HIP_MEMORY_SCOPE_AGENT);
    }
    int mode;
    while ((mode = __hip_atomic_load(&ctrs[10], __ATOMIC_RELAXED,
                                     __HIP_MEMORY_SCOPE_AGENT)) == 0)
      __builtin_amdgcn_s_sleep(2);
    int layer = -1, p = 0, slice = 0;
    if (mode == 1) {                                 // FAST: role = (XCD, slot)
      if (xcc < 4 && slot < 32) { layer = xcc >> 1; p = xcc & 1; slice = slot; }
    } else {                                         // FALLBACK: role = global ticket
      if (g < 128) { layer = (g >> 6) & 1; p = (g >> 5) & 1; slice = g & 31; }
    }
    roleShare[0] = mode; roleShare[1] = layer; roleShare[2] = p; roleShare[3] = slice;
  }
  __syncthreads();
  const int mode  = roleShare[0];
  const int layer = roleShare[1];
  const int p     = roleShare[2];
  const int slice = roleShare[3];
  __syncthreads();                                   // reads done before wlds overwrite
  if (layer < 0) return;                             // uniform exit (whole WG)
  const bool fastm = (mode == 1);
  const int K1fast = fastm ? 24 : 0;

  const int j0 = slice << 4;                         // first owned h-column (16 cols)
  const int b0 = p << 5;                             // first owned batch row (32 rows)

  const unsigned short* Wf = layer ? Wf1 : Wf0;
  const float* bi = layer ? bi1 : bi0;
  unsigned short* selfH = layer ? h1 : h0;

  // stage weight slice into LDS (16B units, unit index XOR-swizzled by n&15)
  for (int idx = tid; idx < 8192; idx += 128) {
    int n = idx >> 7;                                // local gate row 0..63
    int u = idx & 127;                               // 16B unit within row
    int G = ((n >> 4) << 9) + j0 + (n & 15);         // gate = q*512 + j0 + jl
    const unsigned short* sp = Wf + ((size_t)G << 10) + ((size_t)u << 3);
    *(uint4*)&wlds[n][(u ^ (n & 15)) << 3] = *(const uint4*)sp;
  }
  __syncthreads();

  const int c15 = lane & 15;
  const int g4  = lane >> 4;
  const int sw  = c15;                               // XOR swizzle key
  const int brow = b0 + (wr << 4) + c15;             // batch row this lane owns
  const int jb   = j0 + (g4 << 2);                   // first of lane's 4 j-cols
  const size_t arow = (size_t)brow * HDIM;
  const size_t hoff = arow + jb;

  const float4 bq0 = *(const float4*)&bi[jb];        // i-gate bias
  const float4 bq1 = *(const float4*)&bi[512 + jb];  // o
  const float4 bq2 = *(const float4*)&bi[1024 + jb]; // z
  const float4 bq3 = *(const float4*)&bi[1536 + jb]; // f

  float cs0 = 0.0f, cs1 = 0.0f, cs2 = 0.0f, cs3 = 0.0f;  // cell state, 4 j's

#define CONSUME(R, KK, UB) do {                                                        \
    f16x8 a = __builtin_bit_cast(f16x8, (R));                                          \
    int u_ = ((UB) + ((KK) << 2) + g4) ^ sw;                                           \
    f16x8 w0 = *(const f16x8*)&wlds[c15][u_ << 3];                                     \
    f16x8 w1 = *(const f16x8*)&wlds[16 + c15][u_ << 3];                                \
    f16x8 w2 = *(const f16x8*)&wlds[32 + c15][u_ << 3];                                \
    f16x8 w3 = *(const f16x8*)&wlds[48 + c15][u_ << 3];                                \
    acc0 = __builtin_amdgcn_mfma_f32_16x16x32_f16(w0, a, acc0, 0, 0, 0);               \
    acc1 = __builtin_amdgcn_mfma_f32_16x16x32_f16(w1, a, acc1, 0, 0, 0);               \
    acc2 = __builtin_amdgcn_mfma_f32_16x16x32_f16(w2, a, acc2, 0, 0, 0);               \
    acc3 = __builtin_amdgcn_mfma_f32_16x16x32_f16(w3, a, acc3, 0, 0, 0);               \
  } while (0)

#define CONSUME_ALL(P, UB)                                                             \
    CONSUME(P##0, 0, UB);  CONSUME(P##1, 1, UB);  CONSUME(P##2, 2, UB);                \
    CONSUME(P##3, 3, UB);  CONSUME(P##4, 4, UB);  CONSUME(P##5, 5, UB);                \
    CONSUME(P##6, 6, UB);  CONSUME(P##7, 7, UB);  CONSUME(P##8, 8, UB);                \
    CONSUME(P##9, 9, UB);  CONSUME(P##10, 10, UB); CONSUME(P##11, 11, UB);             \
    CONSUME(P##12, 12, UB); CONSUME(P##13, 13, UB); CONSUME(P##14, 14, UB);            \
    CONSUME(P##15, 15, UB)

#define LD1X(R, OFFTOK, HP)                                                            \
    asm volatile("global_load_dwordx4 %0, %1, off " OFFTOK " sc0 sc1"                  \
                 : "=v"(R) : "v"(HP) : "memory")
#define LD1P(R, OFFTOK, HP)                                                            \
    asm volatile("global_load_dwordx4 %0, %1, off " OFFTOK                             \
                 : "=v"(R) : "v"(HP) : "memory")

#define ISSUE16X(HP, P) do {                                                           \
    LD1X(P##0, "", HP);            LD1X(P##1, "offset:64", HP);                        \
    LD1X(P##2, "offset:128", HP);  LD1X(P##3, "offset:192", HP);                       \
    LD1X(P##4, "offset:256", HP);  LD1X(P##5, "offset:320", HP);                       \
    LD1X(P##6, "offset:384", HP);  LD1X(P##7, "offset:448", HP);                       \
    LD1X(P##8, "offset:512", HP);  LD1X(P##9, "offset:576", HP);                       \
    LD1X(P##10, "offset:640", HP); LD1X(P##11, "offset:704", HP);                      \
    LD1X(P##12, "offset:768", HP); LD1X(P##13, "offset:832", HP);                      \
    LD1X(P##14, "offset:896", HP); LD1X(P##15, "offset:960", HP);                      \
  } while (0)

#define ISSUE16P(HP, P) do {                                                           \
    LD1P(P##0, "", HP);            LD1P(P##1, "offset:64", HP);                        \
    LD1P(P##2, "offset:128", HP);  LD1P(P##3, "offset:192", HP);                       \
    LD1P(P##4, "offset:256", HP);  LD1P(P##5, "offset:320", HP);                       \
    LD1P(P##6, "offset:384", HP);  LD1P(P##7, "offset:448", HP);                       \
    LD1P(P##8, "offset:512", HP);  LD1P(P##9, "offset:576", HP);                       \
    LD1P(P##10, "offset:640", HP); LD1P(P##11, "offset:704", HP);                      \
    LD1P(P##12, "offset:768", HP); LD1P(P##13, "offset:832", HP);                      \
    LD1P(P##14, "offset:896", HP); LD1P(P##15, "offset:960", HP);                      \
  } while (0)

#define BAD1(R) ((R[0] == SENT) | (R[1] == SENT) | (R[2] == SENT) | (R[3] == SENT))

// Tiered selective retry: sc1-only (device scope, bypasses L1; serves from XCD L2
// if it holds the producer's plain-stored line) while it_<K1, then proven sc0sc1.
#define RET(R, K)                                                                      \
    if (__any(BAD1(R))) { ++nbad_;                                                     \
      if (it_ < K1_) {                                                                 \
        asm volatile("global_load_dwordx4 %0, %1, off sc1"                             \
                     : "=v"(R) : "v"(hp_ + ((K) << 5)) : "memory");                    \
      } else {                                                                         \
        asm volatile("global_load_dwordx4 %0, %1, off sc0 sc1"                         \
                     : "=v"(R) : "v"(hp_ + ((K) << 5)) : "memory"); } }

#define VALT(P, HP, K1) do {                                                           \
    const unsigned short* hp_ = (HP);                                                  \
    const int K1_ = (K1);                                                              \
    int it_ = 0;                                                                       \
    for (;;) {                                                                         \
      asm volatile("s_waitcnt vmcnt(0)" ::: "memory");                                 \
      __builtin_amdgcn_sched_barrier(0);                                               \
      int nbad_ = 0;                                                                   \
      RET(P##0, 0)   RET(P##1, 1)   RET(P##2, 2)   RET(P##3, 3)                        \
      RET(P##4, 4)   RET(P##5, 5)   RET(P##6, 6)   RET(P##7, 7)                        \
      RET(P##8, 8)   RET(P##9, 9)   RET(P##10, 10) RET(P##11, 11)                      \
      RET(P##12, 12) RET(P##13, 13) RET(P##14, 14) RET(P##15, 15)                      \
      if (!nbad_) break;                                                               \
      ++it_;                                                                           \
    }                                                                                  \
    __builtin_amdgcn_sched_barrier(0);                                                 \
  } while (0)

// x half: plain cached loads (xh is read-only input, L2-resident per XCD)
#define KHALF_X(AP) do {                                                               \
    const unsigned short* ap_ = (AP) + arow + (g4 << 3);                               \
    _Pragma("unroll")                                                                  \
    for (int kk = 0; kk < 16; ++kk) {                                                  \
      u32x4 rr = *(const u32x4*)(ap_ + (kk << 5));                                     \
      CONSUME(rr, kk, 0);                                                              \
    }                                                                                  \
  } while (0)

#define EPILOGUE(T) do {                                                               \
    unsigned short* hn = selfH + (size_t)((T) + 1) * ACTMAT;                           \
    float gi_, go_, gz_, gf_, h0v, h1v, h2v, h3v;                                      \
    gi_ = fsigmoid(acc0[0] + bq0.x); go_ = fsigmoid(acc1[0] + bq1.x);                  \
    gz_ = fsigmoid(acc2[0] + bq2.x); gf_ = fsigmoid(acc3[0] + bq3.x);                  \
    cs0 = cs0 * gf_ + gz_ - gi_;  h0v = fsigmoid(cs0) - go_;                           \
    gi_ = fsigmoid(acc0[1] + bq0.y); go_ = fsigmoid(acc1[1] + bq1.y);                  \
    gz_ = fsigmoid(acc2[1] + bq2.y); gf_ = fsigmoid(acc3[1] + bq3.y);                  \
    cs1 = cs1 * gf_ + gz_ - gi_;  h1v = fsigmoid(cs1) - go_;                           \
    gi_ = fsigmoid(acc0[2] + bq0.z); go_ = fsigmoid(acc1[2] + bq1.z);                  \
    gz_ = fsigmoid(acc2[2] + bq2.z); gf_ = fsigmoid(acc3[2] + bq3.z);                  \
    cs2 = cs2 * gf_ + gz_ - gi_;  h2v = fsigmoid(cs2) - go_;                           \
    gi_ = fsigmoid(acc0[3] + bq0.w); go_ = fsigmoid(acc1[3] + bq1.w);                  \
    gz_ = fsigmoid(acc2[3] + bq2.w); gf_ = fsigmoid(acc3[3] + bq3.w);                  \
    cs3 = cs3 * gf_ + gz_ - gi_;  h3v = fsigmoid(cs3) - go_;                           \
    u32x2 dv;                                                                          \
    dv[0] = (uint32_t)f2h(h0v) | ((uint32_t)f2h(h1v) << 16);                           \
    dv[1] = (uint32_t)f2h(h2v) | ((uint32_t)f2h(h3v) << 16);                           \
    if (fastm)                                                                         \
      asm volatile("global_store_dwordx2 %0, %1, off"            /* own XCD L2 */      \
                   :: "v"((uint32_t*)(hn + hoff)), "v"(dv) : "memory");                \
    asm volatile("global_store_dwordx2 %0, %1, off sc0 sc1"      /* MALL copy */       \
                 :: "v"((uint32_t*)(hn + hoff)), "v"(dv) : "memory");                  \
    if (layer) {                                                                       \
      float* outp = out + (size_t)(T) * ACTMAT;                                        \
      *(float4*)(outp + hoff) = make_float4(h0v, h1v, h2v, h3v);                       \
    }                                                                                  \
  } while (0)

  if (layer == 0) {
    for (int t = 0; t < TSTEPS; ++t) {
      f32x4 acc0 = {}, acc1 = {}, acc2 = {}, acc3 = {};
      u32x4 ra0, ra1, ra2, ra3, ra4, ra5, ra6, ra7,
            ra8, ra9, ra10, ra11, ra12, ra13, ra14, ra15;
      const unsigned short* hp = h0 + (size_t)t * ACTMAT + arow + (g4 << 3);
      if (fastm) ISSUE16P(hp, ra); else ISSUE16X(hp, ra);   // early issue (self)
      KHALF_X(xh + (size_t)t * ACTMAT);              // independent work (64 MFMAs)
      VALT(ra, hp, K1fast);                          // tiered sentinel spin
      CONSUME_ALL(ra, 64);
      EPILOGUE(t);
    }
  } else {
    for (int t = 0; t < TSTEPS; ++t) {
      f32x4 acc0 = {}, acc1 = {}, acc2 = {}, acc3 = {};
      u32x4 ra0, ra1, ra2, ra3, ra4, ra5, ra6, ra7,
            ra8, ra9, ra10, ra11, ra12, ra13, ra14, ra15;
      u32x4 rb0, rb1, rb2, rb3, rb4, rb5, rb6, rb7,
            rb8, rb9, rb10, rb11, rb12, rb13, rb14, rb15;
      const unsigned short* hpA = h1 + (size_t)t * ACTMAT + arow + (g4 << 3);
      const unsigned short* hpB = h0 + (size_t)(t + 1) * ACTMAT + arow + (g4 << 3);
      ISSUE16X(hpB, rb);                             // cross h0[t+1]: MALL, phase-lagged
      if (fastm) ISSUE16P(hpA, ra); else ISSUE16X(hpA, ra);  // self h1[t]
      VALT(ra, hpA, K1fast);                         // self first: XCD-local fast
      CONSUME_ALL(ra, 64);                           // 64 MFMAs hide cross RT
      VALT(rb, hpB, 0);                              // cross: MALL-only tier
      CONSUME_ALL(rb, 0);
      EPILOGUE(t);
    }
  }
#undef CONSUME
#undef CONSUME_ALL
#undef LD1X
#undef LD1P
#undef ISSUE16X
#undef ISSUE16P
#undef BAD1
#undef RET
#undef VALT
#undef KHALF_X
#undef EPILOGUE
}

// ---------------- launch ----------------

extern "C" void kernel_launch(void* const* d_in, const int* in_sizes, int n_in,
                              void* d_out, int out_size, void* d_ws, size_t ws_size,
                              hipStream_t stream) {
  (void)in_sizes; (void)n_in; (void)out_size; (void)ws_size;
  const float* x   = (const float*)d_in[0];
  const float* Wi0 = (const float*)d_in[1];
  const float* bi0 = (const float*)d_in[2];
  const float* Wh0 = (const float*)d_in[3];
  const float* Wi1 = (const float*)d_in[4];
  const float* bi1 = (const float*)d_in[5];
  const float* Wh1 = (const float*)d_in[6];
  float* out = (float*)d_out;

  char* ws = (char*)d_ws;
  size_t off = 0;
  auto take = [&](size_t bytes) -> void* {
    void* p = ws + off;
    off += (bytes + 255) & ~(size_t)255;
    return p;
  };
  unsigned short* xh  = (unsigned short*)take((size_t)TSTEPS * ACTMAT * 2);        // 33.5 MB
  unsigned short* h0  = (unsigned short*)take((size_t)(TSTEPS + 1) * ACTMAT * 2);  // 33.6 MB
  unsigned short* h1  = (unsigned short*)take((size_t)(TSTEPS + 1) * ACTMAT * 2);  // 33.6 MB
  unsigned short* Wf0 = (unsigned short*)take((size_t)GATE * 1024 * 2);            // 4 MB
  unsigned short* Wf1 = (unsigned short*)take((size_t)GATE * 1024 * 2);            // 4 MB
  int* ctrs           = (int*)take(64);
  // total ~109.2 MB -- identical footprint to rounds 6-11 (all passed)

  // (TSTEPS+1)*ACTMAT ushorts per h buffer -> 2,101,248 16B units; grid 8208*256 exact
  init_h<<<dim3(8208), dim3(256), 0, stream>>>(h0, h1, ctrs);
  convert_x<<<dim3(16384), dim3(256), 0, stream>>>(x, xh);
  split_w<<<dim3(8192), dim3(256), 0, stream>>>(Wi0, Wh0, Wf0);
  split_w<<<dim3(8192), dim3(256), 0, stream>>>(Wi1, Wh1, Wf1);
  sublstm_persistent<<<dim3(NWGTOT), dim3(128), 0, stream>>>(
      xh, h0, h1, Wf0, Wf1, bi0, bi1, out, ctrs);
}